// Round 1
// baseline (2421.645 us; speedup 1.0000x reference)
//
#include <hip/hip_runtime.h>

#define N_NODES 50000
#define E_EDGES 800000
#define D_INF   128
#define D_HIDF  128
#define D_OUTF  40

// ---------------- kernels ----------------

__global__ void k_count(const int* __restrict__ dst, float* __restrict__ counts) {
    int e = blockIdx.x * blockDim.x + threadIdx.x;
    if (e < E_EDGES) atomicAdd(&counts[dst[e]], 1.0f);
}

// WT[k*O + o] = W[o*K + k]
__global__ void k_transpose(const float* __restrict__ W, float* __restrict__ WT,
                            int O, int K) {
    int idx = blockIdx.x * blockDim.x + threadIdx.x;
    if (idx < O * K) {
        int o = idx / K, k = idx - o * K;
        WT[k * O + o] = W[idx];
    }
}

// scatter-add x[src[e], :] into agg[dst[e], :]  (128-wide, float4 per thread)
__global__ void k_scatter128(const int* __restrict__ src, const int* __restrict__ dst,
                             const float* __restrict__ x, float* __restrict__ agg) {
    long long tid = (long long)blockIdx.x * blockDim.x + threadIdx.x;
    int e = (int)(tid >> 5);        // 32 float4-groups per edge
    int g = (int)(tid & 31);
    if (e >= E_EDGES) return;
    int s = src[e], d = dst[e];
    const float4 v = *reinterpret_cast<const float4*>(&x[(long long)s * 128 + g * 4]);
    float* a = &agg[(long long)d * 128 + g * 4];
    atomicAdd(a + 0, v.x);
    atomicAdd(a + 1, v.y);
    atomicAdd(a + 2, v.z);
    atomicAdd(a + 3, v.w);
}

// h[i,o] = relu( (agg1[i,:]/max(c,1)) . W1l[o,:] + x[i,:] . W1r[o,:] + b1[o] )
// block = 256 threads = 2 nodes x 128 outputs
__global__ void k_layer1(const float* __restrict__ x, const float* __restrict__ agg,
                         const float* __restrict__ counts,
                         const float* __restrict__ W1lT, const float* __restrict__ W1rT,
                         const float* __restrict__ b1, float* __restrict__ h) {
    int i = blockIdx.x * 2 + (threadIdx.x >> 7);
    int o = threadIdx.x & 127;
    if (i >= N_NODES) return;
    float inv = 1.0f / fmaxf(counts[i], 1.0f);
    const float* __restrict__ ar = &agg[(long long)i * 128];
    const float* __restrict__ xr = &x[(long long)i * 128];
    float accl = 0.0f, accr = 0.0f;
#pragma unroll 8
    for (int k = 0; k < 128; ++k) {
        accl = fmaf(ar[k], W1lT[k * 128 + o], accl);
        accr = fmaf(xr[k], W1rT[k * 128 + o], accr);
    }
    float v = accl * inv + accr + b1[o];
    h[(long long)i * 128 + o] = fmaxf(v, 0.0f);
}

// y[i,o] = h[i,:] . W2l[o,:]   (O = 40)
__global__ void k_gemm40(const float* __restrict__ hin, const float* __restrict__ WT,
                         float* __restrict__ y) {
    int t = blockIdx.x * blockDim.x + threadIdx.x;
    int i = t / 40, o = t - i * 40;
    if (i >= N_NODES) return;
    const float* __restrict__ hr = &hin[(long long)i * 128];
    float acc = 0.0f;
#pragma unroll 8
    for (int k = 0; k < 128; ++k)
        acc = fmaf(hr[k], WT[k * 40 + o], acc);
    y[(long long)i * 40 + o] = acc;
}

// scatter-add y2[src[e], :] into agg2[dst[e], :]  (40-wide, float4 per thread)
__global__ void k_scatter40(const int* __restrict__ src, const int* __restrict__ dst,
                            const float* __restrict__ y, float* __restrict__ agg) {
    long long tid = (long long)blockIdx.x * blockDim.x + threadIdx.x;
    int e = (int)(tid / 10);        // 10 float4-groups per edge
    int g = (int)(tid - (long long)e * 10);
    if (e >= E_EDGES) return;
    int s = src[e], d = dst[e];
    const float4 v = *reinterpret_cast<const float4*>(&y[(long long)s * 40 + g * 4]);
    float* a = &agg[(long long)d * 40 + g * 4];
    atomicAdd(a + 0, v.x);
    atomicAdd(a + 1, v.y);
    atomicAdd(a + 2, v.z);
    atomicAdd(a + 3, v.w);
}

// out[i,o] = agg2[i,o]/max(c,1) + b2[o] + h[i,:] . W2r[o,:]
__global__ void k_layer2(const float* __restrict__ h, const float* __restrict__ agg2,
                         const float* __restrict__ counts,
                         const float* __restrict__ W2rT, const float* __restrict__ b2,
                         float* __restrict__ out) {
    int t = blockIdx.x * blockDim.x + threadIdx.x;
    int i = t / 40, o = t - i * 40;
    if (i >= N_NODES) return;
    float inv = 1.0f / fmaxf(counts[i], 1.0f);
    const float* __restrict__ hr = &h[(long long)i * 128];
    float acc = 0.0f;
#pragma unroll 8
    for (int k = 0; k < 128; ++k)
        acc = fmaf(hr[k], W2rT[k * 40 + o], acc);
    out[(long long)i * 40 + o] = agg2[(long long)i * 40 + o] * inv + b2[o] + acc;
}

// ---------------- launch ----------------

extern "C" void kernel_launch(void* const* d_in, const int* in_sizes, int n_in,
                              void* d_out, int out_size, void* d_ws, size_t ws_size,
                              hipStream_t stream) {
    const float* x   = (const float*)d_in[0];
    const int*   ei  = (const int*)d_in[1];      // [2, E] int32
    const float* W1l = (const float*)d_in[2];
    const float* b1  = (const float*)d_in[3];
    const float* W1r = (const float*)d_in[4];
    const float* W2l = (const float*)d_in[5];
    const float* b2  = (const float*)d_in[6];
    const float* W2r = (const float*)d_in[7];

    const int* src = ei;
    const int* dst = ei + E_EDGES;

    float* ws = (float*)d_ws;
    // workspace layout (element offsets)
    const size_t OFF_CNT  = 0;                         // N
    const size_t OFF_W1LT = 50048;                     // 128*128
    const size_t OFF_W1RT = OFF_W1LT + 16384;          // 128*128
    const size_t OFF_W2LT = OFF_W1RT + 16384;          // 128*40
    const size_t OFF_W2RT = OFF_W2LT + 5120;           // 128*40
    const size_t OFF_AGG1 = OFF_W2RT + 5120;           // N*128
    const size_t OFF_H    = OFF_AGG1 + (size_t)N_NODES * 128;  // N*128
    // y2 / agg2 alias over agg1 region (agg1 dead after k_layer1)
    const size_t OFF_Y2   = OFF_AGG1;                  // N*40
    const size_t OFF_AGG2 = OFF_AGG1 + (size_t)N_NODES * 40;   // N*40

    float* cnt  = ws + OFF_CNT;
    float* w1lt = ws + OFF_W1LT;
    float* w1rt = ws + OFF_W1RT;
    float* w2lt = ws + OFF_W2LT;
    float* w2rt = ws + OFF_W2RT;
    float* agg1 = ws + OFF_AGG1;
    float* h    = ws + OFF_H;
    float* y2   = ws + OFF_Y2;
    float* agg2 = ws + OFF_AGG2;
    float* outp = (float*)d_out;

    // zero counts + agg1
    hipMemsetAsync(cnt, 0, (size_t)N_NODES * sizeof(float), stream);
    hipMemsetAsync(agg1, 0, (size_t)N_NODES * 128 * sizeof(float), stream);

    // degree counts
    k_count<<<(E_EDGES + 255) / 256, 256, 0, stream>>>(dst, cnt);

    // weight transposes
    k_transpose<<<(16384 + 255) / 256, 256, 0, stream>>>(W1l, w1lt, 128, 128);
    k_transpose<<<(16384 + 255) / 256, 256, 0, stream>>>(W1r, w1rt, 128, 128);
    k_transpose<<<(5120 + 255) / 256, 256, 0, stream>>>(W2l, w2lt, 40, 128);
    k_transpose<<<(5120 + 255) / 256, 256, 0, stream>>>(W2r, w2rt, 40, 128);

    // layer 1 aggregation: agg1 += x[src] per edge
    {
        long long total = (long long)E_EDGES * 32;
        int blocks = (int)((total + 255) / 256);
        k_scatter128<<<blocks, 256, 0, stream>>>(src, dst, x, agg1);
    }

    // layer 1 dense + relu
    k_layer1<<<(N_NODES + 1) / 2, 256, 0, stream>>>(x, agg1, cnt, w1lt, w1rt, b1, h);

    // zero agg2 (aliased region is now dead)
    hipMemsetAsync(agg2, 0, (size_t)N_NODES * 40 * sizeof(float), stream);

    // y2 = h @ W2l.T
    {
        long long total = (long long)N_NODES * 40;
        int blocks = (int)((total + 255) / 256);
        k_gemm40<<<blocks, 256, 0, stream>>>(h, w2lt, y2);
    }

    // layer 2 aggregation: agg2 += y2[src] per edge
    {
        long long total = (long long)E_EDGES * 10;
        int blocks = (int)((total + 255) / 256);
        k_scatter40<<<blocks, 256, 0, stream>>>(src, dst, y2, agg2);
    }

    // final output
    {
        long long total = (long long)N_NODES * 40;
        int blocks = (int)((total + 255) / 256);
        k_layer2<<<blocks, 256, 0, stream>>>(h, agg2, cnt, w2rt, b2, outp);
    }
}

// Round 2
// 786.486 us; speedup vs baseline: 3.0791x; 3.0791x over previous
//
#include <hip/hip_runtime.h>

#define N_NODES 50000
#define E_EDGES 800000

// ---------------- CSR build ----------------

__global__ void k_count(const int* __restrict__ dst, int* __restrict__ cnt) {
    int e = blockIdx.x * blockDim.x + threadIdx.x;
    if (e < E_EDGES) atomicAdd(&cnt[dst[e]], 1);
}

#define SCAN_T 1024
__global__ void k_scan(const int* __restrict__ cnt, int* __restrict__ rowptr,
                       int* __restrict__ cursor) {
    __shared__ int part[SCAN_T];
    int t = threadIdx.x;
    const int chunk = (N_NODES + SCAN_T - 1) / SCAN_T;   // 49
    int base = t * chunk;
    int s = 0;
    for (int j = 0; j < chunk; ++j) {
        int i = base + j;
        if (i < N_NODES) s += cnt[i];
    }
    part[t] = s;
    __syncthreads();
    for (int off = 1; off < SCAN_T; off <<= 1) {
        int v = (t >= off) ? part[t - off] : 0;
        __syncthreads();
        part[t] += v;
        __syncthreads();
    }
    int run = (t == 0) ? 0 : part[t - 1];   // exclusive prefix of my chunk
    for (int j = 0; j < chunk; ++j) {
        int i = base + j;
        if (i < N_NODES) {
            rowptr[i] = run;
            cursor[i] = run;
            run += cnt[i];
        }
    }
    if (t == SCAN_T - 1) rowptr[N_NODES] = run;   // == E
}

__global__ void k_fill(const int* __restrict__ src, const int* __restrict__ dst,
                       int* __restrict__ cursor, int* __restrict__ eidx) {
    int e = blockIdx.x * blockDim.x + threadIdx.x;
    if (e < E_EDGES) {
        int p = atomicAdd(&cursor[dst[e]], 1);
        eidx[p] = src[e];
    }
}

// ---------------- weights ----------------

// WT[k*O + o] = W[o*K + k]
__global__ void k_transpose(const float* __restrict__ W, float* __restrict__ WT,
                            int O, int K) {
    int idx = blockIdx.x * blockDim.x + threadIdx.x;
    if (idx < O * K) {
        int o = idx / K, k = idx - o * K;
        WT[k * O + o] = W[idx];
    }
}

// ---------------- layer 1 ----------------

// agg[i,o] = sum_{j in N(i)} x[j,o]   (one block of 128 threads per node)
__global__ void k_gather128(const int* __restrict__ rowptr, const int* __restrict__ eidx,
                            const float* __restrict__ x, float* __restrict__ agg) {
    int i = blockIdx.x;
    int o = threadIdx.x;
    int beg = rowptr[i], end = rowptr[i + 1];
    float acc = 0.0f;
    int j = beg;
    for (; j + 3 < end; j += 4) {
        int s0 = eidx[j], s1 = eidx[j + 1], s2 = eidx[j + 2], s3 = eidx[j + 3];
        float v0 = x[(size_t)s0 * 128 + o];
        float v1 = x[(size_t)s1 * 128 + o];
        float v2 = x[(size_t)s2 * 128 + o];
        float v3 = x[(size_t)s3 * 128 + o];
        acc += v0 + v1 + v2 + v3;
    }
    for (; j < end; ++j)
        acc += x[(size_t)eidx[j] * 128 + o];
    agg[(size_t)i * 128 + o] = acc;
}

// h[i,o] = relu( (agg[i,:]*inv) . W1lT[:,o] + x[i,:] . W1rT[:,o] + b1[o] )
// block = 256 threads = 2 nodes x 128 outputs
__global__ void k_layer1(const float* __restrict__ x, const float* __restrict__ agg,
                         const int* __restrict__ rowptr,
                         const float* __restrict__ W1lT, const float* __restrict__ W1rT,
                         const float* __restrict__ b1, float* __restrict__ h) {
    int i = blockIdx.x * 2 + (threadIdx.x >> 7);
    int o = threadIdx.x & 127;
    if (i >= N_NODES) return;
    int deg = rowptr[i + 1] - rowptr[i];
    float inv = 1.0f / fmaxf((float)deg, 1.0f);
    const float* __restrict__ ar = &agg[(size_t)i * 128];
    const float* __restrict__ xr = &x[(size_t)i * 128];
    float accl = 0.0f, accr = 0.0f;
#pragma unroll 8
    for (int k = 0; k < 128; ++k) {
        accl = fmaf(ar[k], W1lT[k * 128 + o], accl);
        accr = fmaf(xr[k], W1rT[k * 128 + o], accr);
    }
    float v = accl * inv + accr + b1[o];
    h[(size_t)i * 128 + o] = fmaxf(v, 0.0f);
}

// ---------------- layer 2 ----------------

// y[i,o] = h[i,:] . W2lT[:,o]   (O = 40)
__global__ void k_gemm40(const float* __restrict__ hin, const float* __restrict__ WT,
                         float* __restrict__ y) {
    int t = blockIdx.x * blockDim.x + threadIdx.x;
    int i = t / 40, o = t - i * 40;
    if (i >= N_NODES) return;
    const float* __restrict__ hr = &hin[(size_t)i * 128];
    float acc = 0.0f;
#pragma unroll 8
    for (int k = 0; k < 128; ++k)
        acc = fmaf(hr[k], WT[k * 40 + o], acc);
    y[(size_t)i * 40 + o] = acc;
}

// out[i,o] = (sum_{j in N(i)} y2[j,o]) * inv + b2[o] + h[i,:] . W2rT[:,o]
// one block of 64 threads per node (40 active)
__global__ void k_layer2f(const int* __restrict__ rowptr, const int* __restrict__ eidx,
                          const float* __restrict__ y2, const float* __restrict__ h,
                          const float* __restrict__ W2rT, const float* __restrict__ b2,
                          float* __restrict__ out) {
    int i = blockIdx.x;
    int o = threadIdx.x;
    if (o >= 40) return;
    int beg = rowptr[i], end = rowptr[i + 1];
    float acc = 0.0f;
    int j = beg;
    for (; j + 3 < end; j += 4) {
        int s0 = eidx[j], s1 = eidx[j + 1], s2 = eidx[j + 2], s3 = eidx[j + 3];
        float v0 = y2[(size_t)s0 * 40 + o];
        float v1 = y2[(size_t)s1 * 40 + o];
        float v2 = y2[(size_t)s2 * 40 + o];
        float v3 = y2[(size_t)s3 * 40 + o];
        acc += v0 + v1 + v2 + v3;
    }
    for (; j < end; ++j)
        acc += y2[(size_t)eidx[j] * 40 + o];
    float inv = 1.0f / fmaxf((float)(end - beg), 1.0f);
    const float* __restrict__ hr = &h[(size_t)i * 128];
    float r = 0.0f;
#pragma unroll 8
    for (int k = 0; k < 128; ++k)
        r = fmaf(hr[k], W2rT[k * 40 + o], r);
    out[(size_t)i * 40 + o] = acc * inv + b2[o] + r;
}

// ---------------- launch ----------------

extern "C" void kernel_launch(void* const* d_in, const int* in_sizes, int n_in,
                              void* d_out, int out_size, void* d_ws, size_t ws_size,
                              hipStream_t stream) {
    const float* x   = (const float*)d_in[0];
    const int*   ei  = (const int*)d_in[1];      // [2, E] int32
    const float* W1l = (const float*)d_in[2];
    const float* b1  = (const float*)d_in[3];
    const float* W1r = (const float*)d_in[4];
    const float* W2l = (const float*)d_in[5];
    const float* b2  = (const float*)d_in[6];
    const float* W2r = (const float*)d_in[7];

    const int* src = ei;
    const int* dst = ei + E_EDGES;

    // ---- workspace carve (16B-aligned) ----
    char* base = (char*)d_ws;
    size_t off = 0;
    auto carve = [&](size_t bytes) {
        void* p = base + off;
        off += (bytes + 15) & ~(size_t)15;
        return p;
    };
    int*   cnt    = (int*)  carve((size_t)N_NODES * 4);
    int*   rowptr = (int*)  carve((size_t)(N_NODES + 1) * 4);
    int*   cursor = (int*)  carve((size_t)N_NODES * 4);
    int*   eidx   = (int*)  carve((size_t)E_EDGES * 4);
    float* w1lt   = (float*)carve(16384 * 4);
    float* w1rt   = (float*)carve(16384 * 4);
    float* w2lt   = (float*)carve(5120 * 4);
    float* w2rt   = (float*)carve(5120 * 4);
    float* agg1   = (float*)carve((size_t)N_NODES * 128 * 4);
    float* h      = (float*)carve((size_t)N_NODES * 128 * 4);
    float* y2     = agg1;   // agg1 dead after k_layer1; alias
    float* outp   = (float*)d_out;

    // ---- CSR build ----
    hipMemsetAsync(cnt, 0, (size_t)N_NODES * 4, stream);
    k_count<<<(E_EDGES + 255) / 256, 256, 0, stream>>>(dst, cnt);
    k_scan<<<1, SCAN_T, 0, stream>>>(cnt, rowptr, cursor);
    k_fill<<<(E_EDGES + 255) / 256, 256, 0, stream>>>(src, dst, cursor, eidx);

    // ---- weight transposes ----
    k_transpose<<<(16384 + 255) / 256, 256, 0, stream>>>(W1l, w1lt, 128, 128);
    k_transpose<<<(16384 + 255) / 256, 256, 0, stream>>>(W1r, w1rt, 128, 128);
    k_transpose<<<(5120 + 255) / 256, 256, 0, stream>>>(W2l, w2lt, 40, 128);
    k_transpose<<<(5120 + 255) / 256, 256, 0, stream>>>(W2r, w2rt, 40, 128);

    // ---- layer 1 ----
    k_gather128<<<N_NODES, 128, 0, stream>>>(rowptr, eidx, x, agg1);
    k_layer1<<<(N_NODES + 1) / 2, 256, 0, stream>>>(x, agg1, rowptr, w1lt, w1rt, b1, h);

    // ---- layer 2 ----
    {
        long long total = (long long)N_NODES * 40;
        int blocks = (int)((total + 255) / 256);
        k_gemm40<<<blocks, 256, 0, stream>>>(h, w2lt, y2);
    }
    k_layer2f<<<N_NODES, 64, 0, stream>>>(rowptr, eidx, y2, h, w2rt, b2, outp);
}

// Round 3
// 389.656 us; speedup vs baseline: 6.2148x; 2.0184x over previous
//
#include <hip/hip_runtime.h>

#define N_NODES 50000
#define E_EDGES 800000

// ---------------- CSR build ----------------

__global__ void k_count(const int* __restrict__ dst, int* __restrict__ cnt) {
    int e = blockIdx.x * blockDim.x + threadIdx.x;
    if (e < E_EDGES) atomicAdd(&cnt[dst[e]], 1);
}

#define SCAN_T 1024
__global__ void k_scan(const int* __restrict__ cnt, int* __restrict__ rowptr,
                       int* __restrict__ cursor) {
    __shared__ int part[SCAN_T];
    int t = threadIdx.x;
    const int chunk = (N_NODES + SCAN_T - 1) / SCAN_T;   // 49
    int base = t * chunk;
    int s = 0;
    for (int j = 0; j < chunk; ++j) {
        int i = base + j;
        if (i < N_NODES) s += cnt[i];
    }
    part[t] = s;
    __syncthreads();
    for (int off = 1; off < SCAN_T; off <<= 1) {
        int v = (t >= off) ? part[t - off] : 0;
        __syncthreads();
        part[t] += v;
        __syncthreads();
    }
    int run = (t == 0) ? 0 : part[t - 1];
    for (int j = 0; j < chunk; ++j) {
        int i = base + j;
        if (i < N_NODES) {
            rowptr[i] = run;
            cursor[i] = run;
            run += cnt[i];
        }
    }
    if (t == SCAN_T - 1) rowptr[N_NODES] = run;
}

__global__ void k_fill(const int* __restrict__ src, const int* __restrict__ dst,
                       int* __restrict__ cursor, int* __restrict__ eidx) {
    int e = blockIdx.x * blockDim.x + threadIdx.x;
    if (e < E_EDGES) {
        int p = atomicAdd(&cursor[dst[e]], 1);
        eidx[p] = src[e];
    }
}

// ---------------- weights ----------------

// WT[k*ldd + col_off + o] = W[o*K + k]
__global__ void k_transpose(const float* __restrict__ W, float* __restrict__ WT,
                            int O, int K, int ldd, int col_off) {
    int idx = blockIdx.x * blockDim.x + threadIdx.x;
    if (idx < O * K) {
        int o = idx / K, k = idx - o * K;
        WT[k * ldd + col_off + o] = W[idx];
    }
}

// ---------------- gathers ----------------

// mean[i,o] = (1/max(deg,1)) * sum_{j in N(i)} x[j,o]   (128 threads / node)
__global__ void k_gather128(const int* __restrict__ rowptr, const int* __restrict__ eidx,
                            const float* __restrict__ x, float* __restrict__ mean) {
    int i = blockIdx.x;
    int o = threadIdx.x;
    int beg = rowptr[i], end = rowptr[i + 1];
    float acc = 0.0f;
    int j = beg;
    for (; j + 3 < end; j += 4) {
        int s0 = eidx[j], s1 = eidx[j + 1], s2 = eidx[j + 2], s3 = eidx[j + 3];
        float v0 = x[(size_t)s0 * 128 + o];
        float v1 = x[(size_t)s1 * 128 + o];
        float v2 = x[(size_t)s2 * 128 + o];
        float v3 = x[(size_t)s3 * 128 + o];
        acc += v0 + v1 + v2 + v3;
    }
    for (; j < end; ++j)
        acc += x[(size_t)eidx[j] * 128 + o];
    float inv = 1.0f / fmaxf((float)(end - beg), 1.0f);
    mean[(size_t)i * 128 + o] = acc * inv;
}

// out[i,o] = z[i,80][40+o] + inv * sum_{j in N(i)} z[j,80][o]   (o < 40)
__global__ void k_gather40(const int* __restrict__ rowptr, const int* __restrict__ eidx,
                           const float* __restrict__ z, float* __restrict__ out) {
    int i = blockIdx.x;
    int o = threadIdx.x;
    if (o >= 40) return;
    int beg = rowptr[i], end = rowptr[i + 1];
    float acc = 0.0f;
    int j = beg;
    for (; j + 3 < end; j += 4) {
        int s0 = eidx[j], s1 = eidx[j + 1], s2 = eidx[j + 2], s3 = eidx[j + 3];
        float v0 = z[(size_t)s0 * 80 + o];
        float v1 = z[(size_t)s1 * 80 + o];
        float v2 = z[(size_t)s2 * 80 + o];
        float v3 = z[(size_t)s3 * 80 + o];
        acc += v0 + v1 + v2 + v3;
    }
    for (; j < end; ++j)
        acc += z[(size_t)eidx[j] * 80 + o];
    float inv = 1.0f / fmaxf((float)(end - beg), 1.0f);
    out[(size_t)i * 40 + o] = z[(size_t)i * 80 + 40 + o] + acc * inv;
}

// ---------------- layer 1 dense ----------------
// h[M,128] = relu( [mean | x][M,256] @ B1cat[256,128] + b1 )
// block 256 thr: og = t&15 (8 outs), mg = t>>4 (4 nodes). BM=64, BK=64.
__launch_bounds__(256)
__global__ void k_dense1(const float* __restrict__ mean, const float* __restrict__ x,
                         const float* __restrict__ Bcat,  // [256][128]
                         const float* __restrict__ b1, float* __restrict__ h) {
    __shared__ float Bs[64][128];
    int t = threadIdx.x;
    int og = t & 15, mg = t >> 4;
    int o0 = og * 8;
    int node0 = blockIdx.x * 64 + mg * 4;

    int mc0 = min(node0 + 0, N_NODES - 1);
    int mc1 = min(node0 + 1, N_NODES - 1);
    int mc2 = min(node0 + 2, N_NODES - 1);
    int mc3 = min(node0 + 3, N_NODES - 1);

    float acc[4][8];
#pragma unroll
    for (int j = 0; j < 4; ++j)
#pragma unroll
        for (int q = 0; q < 8; ++q) acc[j][q] = 0.0f;

    for (int kt = 0; kt < 4; ++kt) {
        const float* __restrict__ Asrc = (kt < 2) ? mean : x;
        int kbase = (kt & 1) * 64;

        __syncthreads();
        {
            const float4* src = (const float4*)(Bcat + kt * 64 * 128);
            float4* dst = (float4*)&Bs[0][0];
#pragma unroll
            for (int p = 0; p < 8; ++p)
                dst[t + p * 256] = src[t + p * 256];
        }
        __syncthreads();

        const float* a0 = Asrc + (size_t)mc0 * 128 + kbase;
        const float* a1 = Asrc + (size_t)mc1 * 128 + kbase;
        const float* a2 = Asrc + (size_t)mc2 * 128 + kbase;
        const float* a3 = Asrc + (size_t)mc3 * 128 + kbase;

#pragma unroll 4
        for (int kk = 0; kk < 64; ++kk) {
            float4 bq0 = *(const float4*)&Bs[kk][o0];
            float4 bq1 = *(const float4*)&Bs[kk][o0 + 4];
            float av[4] = {a0[kk], a1[kk], a2[kk], a3[kk]};
#pragma unroll
            for (int j = 0; j < 4; ++j) {
                acc[j][0] = fmaf(av[j], bq0.x, acc[j][0]);
                acc[j][1] = fmaf(av[j], bq0.y, acc[j][1]);
                acc[j][2] = fmaf(av[j], bq0.z, acc[j][2]);
                acc[j][3] = fmaf(av[j], bq0.w, acc[j][3]);
                acc[j][4] = fmaf(av[j], bq1.x, acc[j][4]);
                acc[j][5] = fmaf(av[j], bq1.y, acc[j][5]);
                acc[j][6] = fmaf(av[j], bq1.z, acc[j][6]);
                acc[j][7] = fmaf(av[j], bq1.w, acc[j][7]);
            }
        }
    }

    float bias[8];
#pragma unroll
    for (int q = 0; q < 8; ++q) bias[q] = b1[o0 + q];

#pragma unroll
    for (int j = 0; j < 4; ++j) {
        int m = node0 + j;
        if (m < N_NODES) {
            float4 r0, r1;
            r0.x = fmaxf(acc[j][0] + bias[0], 0.0f);
            r0.y = fmaxf(acc[j][1] + bias[1], 0.0f);
            r0.z = fmaxf(acc[j][2] + bias[2], 0.0f);
            r0.w = fmaxf(acc[j][3] + bias[3], 0.0f);
            r1.x = fmaxf(acc[j][4] + bias[4], 0.0f);
            r1.y = fmaxf(acc[j][5] + bias[5], 0.0f);
            r1.z = fmaxf(acc[j][6] + bias[6], 0.0f);
            r1.w = fmaxf(acc[j][7] + bias[7], 0.0f);
            *(float4*)&h[(size_t)m * 128 + o0] = r0;
            *(float4*)&h[(size_t)m * 128 + o0 + 4] = r1;
        }
    }
}

// ---------------- layer 2 dense ----------------
// z[M,80] = h[M,128] @ B2cat[128,80];  cols >=40 get +b2
// block 256 thr: og = t&7 (10 outs), mg = t>>3 (4 nodes). BM=128, K=128 one tile.
__launch_bounds__(256)
__global__ void k_dense2(const float* __restrict__ h,
                         const float* __restrict__ Bcat,  // [128][80]
                         const float* __restrict__ b2, float* __restrict__ z) {
    __shared__ float Bs[128][80];
    int t = threadIdx.x;
    int og = t & 7, mg = t >> 3;
    int o0 = og * 10;
    int node0 = blockIdx.x * 128 + mg * 4;

    int mc0 = min(node0 + 0, N_NODES - 1);
    int mc1 = min(node0 + 1, N_NODES - 1);
    int mc2 = min(node0 + 2, N_NODES - 1);
    int mc3 = min(node0 + 3, N_NODES - 1);

    {
        const float4* src = (const float4*)Bcat;
        float4* dst = (float4*)&Bs[0][0];
#pragma unroll
        for (int p = 0; p < 10; ++p)
            dst[t + p * 256] = src[t + p * 256];
    }
    __syncthreads();

    float acc[4][10];
#pragma unroll
    for (int j = 0; j < 4; ++j)
#pragma unroll
        for (int q = 0; q < 10; ++q) acc[j][q] = 0.0f;

    const float* a0 = h + (size_t)mc0 * 128;
    const float* a1 = h + (size_t)mc1 * 128;
    const float* a2 = h + (size_t)mc2 * 128;
    const float* a3 = h + (size_t)mc3 * 128;

#pragma unroll 2
    for (int kk = 0; kk < 128; ++kk) {
        float bv[10];
#pragma unroll
        for (int q = 0; q < 5; ++q) {
            float2 b2v = *(const float2*)&Bs[kk][o0 + 2 * q];
            bv[2 * q] = b2v.x;
            bv[2 * q + 1] = b2v.y;
        }
        float av[4] = {a0[kk], a1[kk], a2[kk], a3[kk]};
#pragma unroll
        for (int j = 0; j < 4; ++j)
#pragma unroll
            for (int q = 0; q < 10; ++q)
                acc[j][q] = fmaf(av[j], bv[q], acc[j][q]);
    }

    float bias[10];
#pragma unroll
    for (int q = 0; q < 10; ++q) {
        int o = o0 + q;
        bias[q] = (o >= 40) ? b2[o - 40] : 0.0f;
    }

#pragma unroll
    for (int j = 0; j < 4; ++j) {
        int m = node0 + j;
        if (m < N_NODES) {
#pragma unroll
            for (int q = 0; q < 5; ++q) {
                float2 r;
                r.x = acc[j][2 * q] + bias[2 * q];
                r.y = acc[j][2 * q + 1] + bias[2 * q + 1];
                *(float2*)&z[(size_t)m * 80 + o0 + 2 * q] = r;
            }
        }
    }
}

// ---------------- launch ----------------

extern "C" void kernel_launch(void* const* d_in, const int* in_sizes, int n_in,
                              void* d_out, int out_size, void* d_ws, size_t ws_size,
                              hipStream_t stream) {
    const float* x   = (const float*)d_in[0];
    const int*   ei  = (const int*)d_in[1];      // [2, E] int32
    const float* W1l = (const float*)d_in[2];
    const float* b1  = (const float*)d_in[3];
    const float* W1r = (const float*)d_in[4];
    const float* W2l = (const float*)d_in[5];
    const float* b2  = (const float*)d_in[6];
    const float* W2r = (const float*)d_in[7];

    const int* src = ei;
    const int* dst = ei + E_EDGES;

    // ---- workspace carve (16B-aligned) ----
    char* base = (char*)d_ws;
    size_t off = 0;
    auto carve = [&](size_t bytes) {
        void* p = base + off;
        off += (bytes + 15) & ~(size_t)15;
        return p;
    };
    int*   cnt    = (int*)  carve((size_t)N_NODES * 4);
    int*   rowptr = (int*)  carve((size_t)(N_NODES + 1) * 4);
    int*   cursor = (int*)  carve((size_t)N_NODES * 4);
    int*   eidx   = (int*)  carve((size_t)E_EDGES * 4);
    float* b1cat  = (float*)carve((size_t)256 * 128 * 4);   // [256][128]
    float* b2cat  = (float*)carve((size_t)128 * 80 * 4);    // [128][80]
    float* mean   = (float*)carve((size_t)N_NODES * 128 * 4);
    float* h      = (float*)carve((size_t)N_NODES * 128 * 4);
    float* z      = mean;   // mean dead after k_dense1; z is N*80 < N*128
    float* outp   = (float*)d_out;

    // ---- CSR build ----
    hipMemsetAsync(cnt, 0, (size_t)N_NODES * 4, stream);
    k_count<<<(E_EDGES + 255) / 256, 256, 0, stream>>>(dst, cnt);
    k_scan<<<1, SCAN_T, 0, stream>>>(cnt, rowptr, cursor);
    k_fill<<<(E_EDGES + 255) / 256, 256, 0, stream>>>(src, dst, cursor, eidx);

    // ---- weight prep ----
    k_transpose<<<(16384 + 255) / 256, 256, 0, stream>>>(W1l, b1cat, 128, 128, 128, 0);
    k_transpose<<<(16384 + 255) / 256, 256, 0, stream>>>(W1r, b1cat + 128 * 128, 128, 128, 128, 0);
    k_transpose<<<(5120 + 255) / 256, 256, 0, stream>>>(W2l, b2cat, 40, 128, 80, 0);
    k_transpose<<<(5120 + 255) / 256, 256, 0, stream>>>(W2r, b2cat, 40, 128, 80, 40);

    // ---- layer 1 ----
    k_gather128<<<N_NODES, 128, 0, stream>>>(rowptr, eidx, x, mean);
    k_dense1<<<(N_NODES + 63) / 64, 256, 0, stream>>>(mean, x, b1cat, b1, h);

    // ---- layer 2 ----
    k_dense2<<<(N_NODES + 127) / 128, 256, 0, stream>>>(h, b2cat, b2, z);
    k_gather40<<<N_NODES, 64, 0, stream>>>(rowptr, eidx, z, outp);
}

// Round 4
// 278.983 us; speedup vs baseline: 8.6802x; 1.3967x over previous
//
#include <hip/hip_runtime.h>

#define N_NODES 50000
#define E_EDGES 800000
#define SCAN_NBLK 196   // ceil(50000/256)

// ---------------- CSR build ----------------

__global__ void k_count(const int* __restrict__ dst, int* __restrict__ cnt) {
    int e = blockIdx.x * blockDim.x + threadIdx.x;
    if (e < E_EDGES) atomicAdd(&cnt[dst[e]], 1);
}

// phase A: per-block exclusive scan of cnt -> excl (in-place ok), block sums -> bsum
__global__ void k_scan_part(const int* __restrict__ cnt, int* __restrict__ excl,
                            int* __restrict__ bsum) {
    __shared__ int sm[256];
    int b = blockIdx.x, t = threadIdx.x;
    int i = b * 256 + t;
    int v = (i < N_NODES) ? cnt[i] : 0;
    sm[t] = v;
    __syncthreads();
    for (int off = 1; off < 256; off <<= 1) {
        int u = (t >= off) ? sm[t - off] : 0;
        __syncthreads();
        sm[t] += u;
        __syncthreads();
    }
    if (i < N_NODES) excl[i] = sm[t] - v;
    if (t == 255) bsum[b] = sm[255];
}

// phase B: exclusive scan of the block sums (SCAN_NBLK <= 256)
__global__ void k_scan_bsum(const int* __restrict__ bsum, int* __restrict__ boff) {
    __shared__ int sm[256];
    int t = threadIdx.x;
    int v = (t < SCAN_NBLK) ? bsum[t] : 0;
    sm[t] = v;
    __syncthreads();
    for (int off = 1; off < 256; off <<= 1) {
        int u = (t >= off) ? sm[t - off] : 0;
        __syncthreads();
        sm[t] += u;
        __syncthreads();
    }
    if (t < SCAN_NBLK) boff[t] = sm[t] - v;
}

// phase C: add block offsets, produce rowptr + cursor
__global__ void k_scan_add(int* __restrict__ rowptr, const int* __restrict__ boff,
                           int* __restrict__ cursor) {
    int b = blockIdx.x, t = threadIdx.x;
    int i = b * 256 + t;
    if (i < N_NODES) {
        int r = rowptr[i] + boff[b];
        rowptr[i] = r;
        cursor[i] = r;
    }
    if (i == 0) rowptr[N_NODES] = E_EDGES;
}

__global__ void k_fill(const int* __restrict__ src, const int* __restrict__ dst,
                       int* __restrict__ cursor, int* __restrict__ eidx) {
    int e = blockIdx.x * blockDim.x + threadIdx.x;
    if (e < E_EDGES) {
        int p = atomicAdd(&cursor[dst[e]], 1);
        eidx[p] = src[e];
    }
}

// ---------------- weights ----------------

// WT[k*ldd + col_off + o] = W[o*K + k]
__global__ void k_transpose(const float* __restrict__ W, float* __restrict__ WT,
                            int O, int K, int ldd, int col_off) {
    int idx = blockIdx.x * blockDim.x + threadIdx.x;
    if (idx < O * K) {
        int o = idx / K, k = idx - o * K;
        WT[k * ldd + col_off + o] = W[idx];
    }
}

// ---------------- gathers ----------------

// mean[i,o] = (1/max(deg,1)) * sum_{j in N(i)} x[j,o]   (128 threads / node)
__global__ void k_gather128(const int* __restrict__ rowptr, const int* __restrict__ eidx,
                            const float* __restrict__ x, float* __restrict__ mean) {
    int i = blockIdx.x;
    int o = threadIdx.x;
    int beg = rowptr[i], end = rowptr[i + 1];
    float acc = 0.0f;
    int j = beg;
    for (; j + 3 < end; j += 4) {
        int s0 = eidx[j], s1 = eidx[j + 1], s2 = eidx[j + 2], s3 = eidx[j + 3];
        float v0 = x[(size_t)s0 * 128 + o];
        float v1 = x[(size_t)s1 * 128 + o];
        float v2 = x[(size_t)s2 * 128 + o];
        float v3 = x[(size_t)s3 * 128 + o];
        acc += v0 + v1 + v2 + v3;
    }
    for (; j < end; ++j)
        acc += x[(size_t)eidx[j] * 128 + o];
    float inv = 1.0f / fmaxf((float)(end - beg), 1.0f);
    mean[(size_t)i * 128 + o] = acc * inv;
}

// out[i,o] = z[i,80][40+o] + inv * sum_{j in N(i)} z[j,80][o]   (o < 40)
__global__ void k_gather40(const int* __restrict__ rowptr, const int* __restrict__ eidx,
                           const float* __restrict__ z, float* __restrict__ out) {
    int i = blockIdx.x;
    int o = threadIdx.x;
    if (o >= 40) return;
    int beg = rowptr[i], end = rowptr[i + 1];
    float acc = 0.0f;
    int j = beg;
    for (; j + 3 < end; j += 4) {
        int s0 = eidx[j], s1 = eidx[j + 1], s2 = eidx[j + 2], s3 = eidx[j + 3];
        float v0 = z[(size_t)s0 * 80 + o];
        float v1 = z[(size_t)s1 * 80 + o];
        float v2 = z[(size_t)s2 * 80 + o];
        float v3 = z[(size_t)s3 * 80 + o];
        acc += v0 + v1 + v2 + v3;
    }
    for (; j < end; ++j)
        acc += z[(size_t)eidx[j] * 80 + o];
    float inv = 1.0f / fmaxf((float)(end - beg), 1.0f);
    out[(size_t)i * 40 + o] = z[(size_t)i * 80 + 40 + o] + acc * inv;
}

// ---------------- layer 1 dense ----------------
// h[M,128] = relu( [mean | x][M,256] @ B1cat[256,128] + b1 )
__launch_bounds__(256)
__global__ void k_dense1(const float* __restrict__ mean, const float* __restrict__ x,
                         const float* __restrict__ Bcat,  // [256][128]
                         const float* __restrict__ b1, float* __restrict__ h) {
    __shared__ float Bs[64][128];
    int t = threadIdx.x;
    int og = t & 15, mg = t >> 4;
    int o0 = og * 8;
    int node0 = blockIdx.x * 64 + mg * 4;

    int mc0 = min(node0 + 0, N_NODES - 1);
    int mc1 = min(node0 + 1, N_NODES - 1);
    int mc2 = min(node0 + 2, N_NODES - 1);
    int mc3 = min(node0 + 3, N_NODES - 1);

    float acc[4][8];
#pragma unroll
    for (int j = 0; j < 4; ++j)
#pragma unroll
        for (int q = 0; q < 8; ++q) acc[j][q] = 0.0f;

    for (int kt = 0; kt < 4; ++kt) {
        const float* __restrict__ Asrc = (kt < 2) ? mean : x;
        int kbase = (kt & 1) * 64;

        __syncthreads();
        {
            const float4* src = (const float4*)(Bcat + kt * 64 * 128);
            float4* dst = (float4*)&Bs[0][0];
#pragma unroll
            for (int p = 0; p < 8; ++p)
                dst[t + p * 256] = src[t + p * 256];
        }
        __syncthreads();

        const float* a0 = Asrc + (size_t)mc0 * 128 + kbase;
        const float* a1 = Asrc + (size_t)mc1 * 128 + kbase;
        const float* a2 = Asrc + (size_t)mc2 * 128 + kbase;
        const float* a3 = Asrc + (size_t)mc3 * 128 + kbase;

#pragma unroll 4
        for (int kk = 0; kk < 64; ++kk) {
            float4 bq0 = *(const float4*)&Bs[kk][o0];
            float4 bq1 = *(const float4*)&Bs[kk][o0 + 4];
            float av[4] = {a0[kk], a1[kk], a2[kk], a3[kk]};
#pragma unroll
            for (int j = 0; j < 4; ++j) {
                acc[j][0] = fmaf(av[j], bq0.x, acc[j][0]);
                acc[j][1] = fmaf(av[j], bq0.y, acc[j][1]);
                acc[j][2] = fmaf(av[j], bq0.z, acc[j][2]);
                acc[j][3] = fmaf(av[j], bq0.w, acc[j][3]);
                acc[j][4] = fmaf(av[j], bq1.x, acc[j][4]);
                acc[j][5] = fmaf(av[j], bq1.y, acc[j][5]);
                acc[j][6] = fmaf(av[j], bq1.z, acc[j][6]);
                acc[j][7] = fmaf(av[j], bq1.w, acc[j][7]);
            }
        }
    }

    float bias[8];
#pragma unroll
    for (int q = 0; q < 8; ++q) bias[q] = b1[o0 + q];

#pragma unroll
    for (int j = 0; j < 4; ++j) {
        int m = node0 + j;
        if (m < N_NODES) {
            float4 r0, r1;
            r0.x = fmaxf(acc[j][0] + bias[0], 0.0f);
            r0.y = fmaxf(acc[j][1] + bias[1], 0.0f);
            r0.z = fmaxf(acc[j][2] + bias[2], 0.0f);
            r0.w = fmaxf(acc[j][3] + bias[3], 0.0f);
            r1.x = fmaxf(acc[j][4] + bias[4], 0.0f);
            r1.y = fmaxf(acc[j][5] + bias[5], 0.0f);
            r1.z = fmaxf(acc[j][6] + bias[6], 0.0f);
            r1.w = fmaxf(acc[j][7] + bias[7], 0.0f);
            *(float4*)&h[(size_t)m * 128 + o0] = r0;
            *(float4*)&h[(size_t)m * 128 + o0 + 4] = r1;
        }
    }
}

// ---------------- layer 2 dense ----------------
// z[M,80] = h[M,128] @ B2cat[128,80];  cols >=40 get +b2
__launch_bounds__(256)
__global__ void k_dense2(const float* __restrict__ h,
                         const float* __restrict__ Bcat,  // [128][80]
                         const float* __restrict__ b2, float* __restrict__ z) {
    __shared__ float Bs[128][80];
    int t = threadIdx.x;
    int og = t & 7, mg = t >> 3;
    int o0 = og * 10;
    int node0 = blockIdx.x * 128 + mg * 4;

    int mc0 = min(node0 + 0, N_NODES - 1);
    int mc1 = min(node0 + 1, N_NODES - 1);
    int mc2 = min(node0 + 2, N_NODES - 1);
    int mc3 = min(node0 + 3, N_NODES - 1);

    {
        const float4* src = (const float4*)Bcat;
        float4* dst = (float4*)&Bs[0][0];
#pragma unroll
        for (int p = 0; p < 10; ++p)
            dst[t + p * 256] = src[t + p * 256];
    }
    __syncthreads();

    float acc[4][10];
#pragma unroll
    for (int j = 0; j < 4; ++j)
#pragma unroll
        for (int q = 0; q < 10; ++q) acc[j][q] = 0.0f;

    const float* a0 = h + (size_t)mc0 * 128;
    const float* a1 = h + (size_t)mc1 * 128;
    const float* a2 = h + (size_t)mc2 * 128;
    const float* a3 = h + (size_t)mc3 * 128;

#pragma unroll 2
    for (int kk = 0; kk < 128; ++kk) {
        float bv[10];
#pragma unroll
        for (int q = 0; q < 5; ++q) {
            float2 b2v = *(const float2*)&Bs[kk][o0 + 2 * q];
            bv[2 * q] = b2v.x;
            bv[2 * q + 1] = b2v.y;
        }
        float av[4] = {a0[kk], a1[kk], a2[kk], a3[kk]};
#pragma unroll
        for (int j = 0; j < 4; ++j)
#pragma unroll
            for (int q = 0; q < 10; ++q)
                acc[j][q] = fmaf(av[j], bv[q], acc[j][q]);
    }

    float bias[10];
#pragma unroll
    for (int q = 0; q < 10; ++q) {
        int o = o0 + q;
        bias[q] = (o >= 40) ? b2[o - 40] : 0.0f;
    }

#pragma unroll
    for (int j = 0; j < 4; ++j) {
        int m = node0 + j;
        if (m < N_NODES) {
#pragma unroll
            for (int q = 0; q < 5; ++q) {
                float2 r;
                r.x = acc[j][2 * q] + bias[2 * q];
                r.y = acc[j][2 * q + 1] + bias[2 * q + 1];
                *(float2*)&z[(size_t)m * 80 + o0 + 2 * q] = r;
            }
        }
    }
}

// ---------------- launch ----------------

extern "C" void kernel_launch(void* const* d_in, const int* in_sizes, int n_in,
                              void* d_out, int out_size, void* d_ws, size_t ws_size,
                              hipStream_t stream) {
    const float* x   = (const float*)d_in[0];
    const int*   ei  = (const int*)d_in[1];      // [2, E] int32
    const float* W1l = (const float*)d_in[2];
    const float* b1  = (const float*)d_in[3];
    const float* W1r = (const float*)d_in[4];
    const float* W2l = (const float*)d_in[5];
    const float* b2  = (const float*)d_in[6];
    const float* W2r = (const float*)d_in[7];

    const int* src = ei;
    const int* dst = ei + E_EDGES;

    // ---- workspace carve (16B-aligned) ----
    char* base = (char*)d_ws;
    size_t off = 0;
    auto carve = [&](size_t bytes) {
        void* p = base + off;
        off += (bytes + 15) & ~(size_t)15;
        return p;
    };
    int*   cnt    = (int*)  carve((size_t)N_NODES * 4);
    int*   rowptr = (int*)  carve((size_t)(N_NODES + 1) * 4);
    int*   cursor = (int*)  carve((size_t)N_NODES * 4);
    int*   eidx   = (int*)  carve((size_t)E_EDGES * 4);
    int*   bsum   = (int*)  carve((size_t)256 * 4);
    int*   boff   = (int*)  carve((size_t)256 * 4);
    float* b1cat  = (float*)carve((size_t)256 * 128 * 4);   // [256][128]
    float* b2cat  = (float*)carve((size_t)128 * 80 * 4);    // [128][80]
    float* mean   = (float*)carve((size_t)N_NODES * 128 * 4);
    float* h      = (float*)carve((size_t)N_NODES * 128 * 4);
    float* z      = mean;   // mean dead after k_dense1; z is N*80 < N*128
    float* outp   = (float*)d_out;

    // ---- CSR build ----
    hipMemsetAsync(cnt, 0, (size_t)N_NODES * 4, stream);
    k_count<<<(E_EDGES + 255) / 256, 256, 0, stream>>>(dst, cnt);
    k_scan_part<<<SCAN_NBLK, 256, 0, stream>>>(cnt, rowptr, bsum);
    k_scan_bsum<<<1, 256, 0, stream>>>(bsum, boff);
    k_scan_add<<<SCAN_NBLK, 256, 0, stream>>>(rowptr, boff, cursor);
    k_fill<<<(E_EDGES + 255) / 256, 256, 0, stream>>>(src, dst, cursor, eidx);

    // ---- weight prep ----
    k_transpose<<<(16384 + 255) / 256, 256, 0, stream>>>(W1l, b1cat, 128, 128, 128, 0);
    k_transpose<<<(16384 + 255) / 256, 256, 0, stream>>>(W1r, b1cat + 128 * 128, 128, 128, 128, 0);
    k_transpose<<<(5120 + 255) / 256, 256, 0, stream>>>(W2l, b2cat, 40, 128, 80, 0);
    k_transpose<<<(5120 + 255) / 256, 256, 0, stream>>>(W2r, b2cat, 40, 128, 80, 40);

    // ---- layer 1 ----
    k_gather128<<<N_NODES, 128, 0, stream>>>(rowptr, eidx, x, mean);
    k_dense1<<<(N_NODES + 63) / 64, 256, 0, stream>>>(mean, x, b1cat, b1, h);

    // ---- layer 2 ----
    k_dense2<<<(N_NODES + 127) / 128, 256, 0, stream>>>(h, b2cat, b2, z);
    k_gather40<<<N_NODES, 64, 0, stream>>>(rowptr, eidx, z, outp);
}

// Round 5
// 272.394 us; speedup vs baseline: 8.8902x; 1.0242x over previous
//
#include <hip/hip_runtime.h>

#define N_NODES 50000
#define E_EDGES 800000
#define SCAN_NBLK 196   // ceil(50000/256)

// ---------------- CSR build ----------------

__global__ void k_count(const int* __restrict__ dst, int* __restrict__ cnt) {
    int e = blockIdx.x * blockDim.x + threadIdx.x;
    if (e < E_EDGES) atomicAdd(&cnt[dst[e]], 1);
}

// phase A: per-block exclusive scan of cnt -> excl (in-place ok), block sums -> bsum
__global__ void k_scan_part(const int* __restrict__ cnt, int* __restrict__ excl,
                            int* __restrict__ bsum) {
    __shared__ int sm[256];
    int b = blockIdx.x, t = threadIdx.x;
    int i = b * 256 + t;
    int v = (i < N_NODES) ? cnt[i] : 0;
    sm[t] = v;
    __syncthreads();
    for (int off = 1; off < 256; off <<= 1) {
        int u = (t >= off) ? sm[t - off] : 0;
        __syncthreads();
        sm[t] += u;
        __syncthreads();
    }
    if (i < N_NODES) excl[i] = sm[t] - v;
    if (t == 255) bsum[b] = sm[255];
}

// phase B: exclusive scan of the block sums (SCAN_NBLK <= 256)
__global__ void k_scan_bsum(const int* __restrict__ bsum, int* __restrict__ boff) {
    __shared__ int sm[256];
    int t = threadIdx.x;
    int v = (t < SCAN_NBLK) ? bsum[t] : 0;
    sm[t] = v;
    __syncthreads();
    for (int off = 1; off < 256; off <<= 1) {
        int u = (t >= off) ? sm[t - off] : 0;
        __syncthreads();
        sm[t] += u;
        __syncthreads();
    }
    if (t < SCAN_NBLK) boff[t] = sm[t] - v;
}

// phase C: add block offsets, produce rowptr + cursor
__global__ void k_scan_add(int* __restrict__ rowptr, const int* __restrict__ boff,
                           int* __restrict__ cursor) {
    int b = blockIdx.x, t = threadIdx.x;
    int i = b * 256 + t;
    if (i < N_NODES) {
        int r = rowptr[i] + boff[b];
        rowptr[i] = r;
        cursor[i] = r;
    }
    if (i == 0) rowptr[N_NODES] = E_EDGES;
}

__global__ void k_fill(const int* __restrict__ src, const int* __restrict__ dst,
                       int* __restrict__ cursor, int* __restrict__ eidx) {
    int e = blockIdx.x * blockDim.x + threadIdx.x;
    if (e < E_EDGES) {
        int p = atomicAdd(&cursor[dst[e]], 1);
        eidx[p] = src[e];
    }
}

// ---------------- weights ----------------

// WT[k*ldd + col_off + o] = W[o*K + k]
__global__ void k_transpose(const float* __restrict__ W, float* __restrict__ WT,
                            int O, int K, int ldd, int col_off) {
    int idx = blockIdx.x * blockDim.x + threadIdx.x;
    if (idx < O * K) {
        int o = idx / K, k = idx - o * K;
        WT[k * ldd + col_off + o] = W[idx];
    }
}

// ---------------- gathers ----------------

// mean[i,o] = (1/max(deg,1)) * sum_{j in N(i)} x[j,o]   (128 threads / node)
__global__ void k_gather128(const int* __restrict__ rowptr, const int* __restrict__ eidx,
                            const float* __restrict__ x, float* __restrict__ mean) {
    int i = blockIdx.x;
    int o = threadIdx.x;
    int beg = rowptr[i], end = rowptr[i + 1];
    float acc = 0.0f;
    int j = beg;
    for (; j + 3 < end; j += 4) {
        int s0 = eidx[j], s1 = eidx[j + 1], s2 = eidx[j + 2], s3 = eidx[j + 3];
        float v0 = x[(size_t)s0 * 128 + o];
        float v1 = x[(size_t)s1 * 128 + o];
        float v2 = x[(size_t)s2 * 128 + o];
        float v3 = x[(size_t)s3 * 128 + o];
        acc += v0 + v1 + v2 + v3;
    }
    for (; j < end; ++j)
        acc += x[(size_t)eidx[j] * 128 + o];
    float inv = 1.0f / fmaxf((float)(end - beg), 1.0f);
    mean[(size_t)i * 128 + o] = acc * inv;
}

// out[i,o] = z[i,80][40+o] + inv * sum_{j in N(i)} z[j,80][o]   (o < 40)
__global__ void k_gather40(const int* __restrict__ rowptr, const int* __restrict__ eidx,
                           const float* __restrict__ z, float* __restrict__ out) {
    int i = blockIdx.x;
    int o = threadIdx.x;
    if (o >= 40) return;
    int beg = rowptr[i], end = rowptr[i + 1];
    float acc = 0.0f;
    int j = beg;
    for (; j + 3 < end; j += 4) {
        int s0 = eidx[j], s1 = eidx[j + 1], s2 = eidx[j + 2], s3 = eidx[j + 3];
        float v0 = z[(size_t)s0 * 80 + o];
        float v1 = z[(size_t)s1 * 80 + o];
        float v2 = z[(size_t)s2 * 80 + o];
        float v3 = z[(size_t)s3 * 80 + o];
        acc += v0 + v1 + v2 + v3;
    }
    for (; j < end; ++j)
        acc += z[(size_t)eidx[j] * 80 + o];
    float inv = 1.0f / fmaxf((float)(end - beg), 1.0f);
    out[(size_t)i * 40 + o] = z[(size_t)i * 80 + 40 + o] + acc * inv;
}

// ---------------- layer 1 dense ----------------
// h[M,128] = relu( [mean | x][M,256] @ B1cat[256,128] + b1 )
// block 256 thr: og = t&15 -> columns {og*4..og*4+3, 64+og*4..+3} (2-way banks, free)
//                mg = t>>4 -> 8 nodes each; BM = 128, BK = 64.
__launch_bounds__(256)
__global__ void k_dense1(const float* __restrict__ mean, const float* __restrict__ x,
                         const float* __restrict__ Bcat,  // [256][128]
                         const float* __restrict__ b1, float* __restrict__ h) {
    __shared__ float Bs[64][128];
    int t = threadIdx.x;
    int og = t & 15, mg = t >> 4;
    int og4 = og * 4;
    int node0 = blockIdx.x * 128 + mg * 8;

    int mr[8];
#pragma unroll
    for (int j = 0; j < 8; ++j)
        mr[j] = min(node0 + j, N_NODES - 1);

    float acc[8][8];
#pragma unroll
    for (int j = 0; j < 8; ++j)
#pragma unroll
        for (int q = 0; q < 8; ++q) acc[j][q] = 0.0f;

    for (int kt = 0; kt < 4; ++kt) {
        const float* __restrict__ Asrc = (kt < 2) ? mean : x;
        int kbase = (kt & 1) * 64;

        __syncthreads();
        {
            const float4* src = (const float4*)(Bcat + kt * 64 * 128);
            float4* dst = (float4*)&Bs[0][0];
#pragma unroll
            for (int p = 0; p < 8; ++p)
                dst[t + p * 256] = src[t + p * 256];
        }
        __syncthreads();

        const float* ap[8];
#pragma unroll
        for (int j = 0; j < 8; ++j)
            ap[j] = Asrc + (size_t)mr[j] * 128 + kbase;

#pragma unroll 2
        for (int k4 = 0; k4 < 16; ++k4) {
            float4 av[8];
#pragma unroll
            for (int j = 0; j < 8; ++j)
                av[j] = *(const float4*)(ap[j] + k4 * 4);

#pragma unroll
            for (int u = 0; u < 4; ++u) {
                int kk = k4 * 4 + u;
                float4 bq0 = *(const float4*)&Bs[kk][og4];
                float4 bq1 = *(const float4*)&Bs[kk][64 + og4];
#pragma unroll
                for (int j = 0; j < 8; ++j) {
                    float a = (u == 0) ? av[j].x : (u == 1) ? av[j].y
                              : (u == 2) ? av[j].z : av[j].w;
                    acc[j][0] = fmaf(a, bq0.x, acc[j][0]);
                    acc[j][1] = fmaf(a, bq0.y, acc[j][1]);
                    acc[j][2] = fmaf(a, bq0.z, acc[j][2]);
                    acc[j][3] = fmaf(a, bq0.w, acc[j][3]);
                    acc[j][4] = fmaf(a, bq1.x, acc[j][4]);
                    acc[j][5] = fmaf(a, bq1.y, acc[j][5]);
                    acc[j][6] = fmaf(a, bq1.z, acc[j][6]);
                    acc[j][7] = fmaf(a, bq1.w, acc[j][7]);
                }
            }
        }
    }

    float bias[8];
#pragma unroll
    for (int q = 0; q < 4; ++q) bias[q] = b1[og4 + q];
#pragma unroll
    for (int q = 0; q < 4; ++q) bias[4 + q] = b1[64 + og4 + q];

#pragma unroll
    for (int j = 0; j < 8; ++j) {
        int m = node0 + j;
        if (m < N_NODES) {
            float4 r0, r1;
            r0.x = fmaxf(acc[j][0] + bias[0], 0.0f);
            r0.y = fmaxf(acc[j][1] + bias[1], 0.0f);
            r0.z = fmaxf(acc[j][2] + bias[2], 0.0f);
            r0.w = fmaxf(acc[j][3] + bias[3], 0.0f);
            r1.x = fmaxf(acc[j][4] + bias[4], 0.0f);
            r1.y = fmaxf(acc[j][5] + bias[5], 0.0f);
            r1.z = fmaxf(acc[j][6] + bias[6], 0.0f);
            r1.w = fmaxf(acc[j][7] + bias[7], 0.0f);
            *(float4*)&h[(size_t)m * 128 + og4] = r0;
            *(float4*)&h[(size_t)m * 128 + 64 + og4] = r1;
        }
    }
}

// ---------------- layer 2 dense ----------------
// z[M,80] = h[M,128] @ B2cat[128,80];  cols >=40 get +b2
__launch_bounds__(256)
__global__ void k_dense2(const float* __restrict__ h,
                         const float* __restrict__ Bcat,  // [128][80]
                         const float* __restrict__ b2, float* __restrict__ z) {
    __shared__ float Bs[128][80];
    int t = threadIdx.x;
    int og = t & 7, mg = t >> 3;
    int o0 = og * 10;
    int node0 = blockIdx.x * 128 + mg * 4;

    int mc0 = min(node0 + 0, N_NODES - 1);
    int mc1 = min(node0 + 1, N_NODES - 1);
    int mc2 = min(node0 + 2, N_NODES - 1);
    int mc3 = min(node0 + 3, N_NODES - 1);

    {
        const float4* src = (const float4*)Bcat;
        float4* dst = (float4*)&Bs[0][0];
#pragma unroll
        for (int p = 0; p < 10; ++p)
            dst[t + p * 256] = src[t + p * 256];
    }
    __syncthreads();

    float acc[4][10];
#pragma unroll
    for (int j = 0; j < 4; ++j)
#pragma unroll
        for (int q = 0; q < 10; ++q) acc[j][q] = 0.0f;

    const float* a0 = h + (size_t)mc0 * 128;
    const float* a1 = h + (size_t)mc1 * 128;
    const float* a2 = h + (size_t)mc2 * 128;
    const float* a3 = h + (size_t)mc3 * 128;

#pragma unroll 2
    for (int kk = 0; kk < 128; ++kk) {
        float bv[10];
#pragma unroll
        for (int q = 0; q < 5; ++q) {
            float2 b2v = *(const float2*)&Bs[kk][o0 + 2 * q];
            bv[2 * q] = b2v.x;
            bv[2 * q + 1] = b2v.y;
        }
        float av[4] = {a0[kk], a1[kk], a2[kk], a3[kk]};
#pragma unroll
        for (int j = 0; j < 4; ++j)
#pragma unroll
            for (int q = 0; q < 10; ++q)
                acc[j][q] = fmaf(av[j], bv[q], acc[j][q]);
    }

    float bias[10];
#pragma unroll
    for (int q = 0; q < 10; ++q) {
        int o = o0 + q;
        bias[q] = (o >= 40) ? b2[o - 40] : 0.0f;
    }

#pragma unroll
    for (int j = 0; j < 4; ++j) {
        int m = node0 + j;
        if (m < N_NODES) {
#pragma unroll
            for (int q = 0; q < 5; ++q) {
                float2 r;
                r.x = acc[j][2 * q] + bias[2 * q];
                r.y = acc[j][2 * q + 1] + bias[2 * q + 1];
                *(float2*)&z[(size_t)m * 80 + o0 + 2 * q] = r;
            }
        }
    }
}

// ---------------- launch ----------------

extern "C" void kernel_launch(void* const* d_in, const int* in_sizes, int n_in,
                              void* d_out, int out_size, void* d_ws, size_t ws_size,
                              hipStream_t stream) {
    const float* x   = (const float*)d_in[0];
    const int*   ei  = (const int*)d_in[1];      // [2, E] int32
    const float* W1l = (const float*)d_in[2];
    const float* b1  = (const float*)d_in[3];
    const float* W1r = (const float*)d_in[4];
    const float* W2l = (const float*)d_in[5];
    const float* b2  = (const float*)d_in[6];
    const float* W2r = (const float*)d_in[7];

    const int* src = ei;
    const int* dst = ei + E_EDGES;

    // ---- workspace carve (16B-aligned) ----
    char* base = (char*)d_ws;
    size_t off = 0;
    auto carve = [&](size_t bytes) {
        void* p = base + off;
        off += (bytes + 15) & ~(size_t)15;
        return p;
    };
    int*   cnt    = (int*)  carve((size_t)N_NODES * 4);
    int*   rowptr = (int*)  carve((size_t)(N_NODES + 1) * 4);
    int*   cursor = (int*)  carve((size_t)N_NODES * 4);
    int*   eidx   = (int*)  carve((size_t)E_EDGES * 4);
    int*   bsum   = (int*)  carve((size_t)256 * 4);
    int*   boff   = (int*)  carve((size_t)256 * 4);
    float* b1cat  = (float*)carve((size_t)256 * 128 * 4);   // [256][128]
    float* b2cat  = (float*)carve((size_t)128 * 80 * 4);    // [128][80]
    float* mean   = (float*)carve((size_t)N_NODES * 128 * 4);
    float* h      = (float*)carve((size_t)N_NODES * 128 * 4);
    float* z      = mean;   // mean dead after k_dense1; z is N*80 < N*128
    float* outp   = (float*)d_out;

    // ---- CSR build ----
    hipMemsetAsync(cnt, 0, (size_t)N_NODES * 4, stream);
    k_count<<<(E_EDGES + 255) / 256, 256, 0, stream>>>(dst, cnt);
    k_scan_part<<<SCAN_NBLK, 256, 0, stream>>>(cnt, rowptr, bsum);
    k_scan_bsum<<<1, 256, 0, stream>>>(bsum, boff);
    k_scan_add<<<SCAN_NBLK, 256, 0, stream>>>(rowptr, boff, cursor);
    k_fill<<<(E_EDGES + 255) / 256, 256, 0, stream>>>(src, dst, cursor, eidx);

    // ---- weight prep ----
    k_transpose<<<(16384 + 255) / 256, 256, 0, stream>>>(W1l, b1cat, 128, 128, 128, 0);
    k_transpose<<<(16384 + 255) / 256, 256, 0, stream>>>(W1r, b1cat + 128 * 128, 128, 128, 128, 0);
    k_transpose<<<(5120 + 255) / 256, 256, 0, stream>>>(W2l, b2cat, 40, 128, 80, 0);
    k_transpose<<<(5120 + 255) / 256, 256, 0, stream>>>(W2r, b2cat, 40, 128, 80, 40);

    // ---- layer 1 ----
    k_gather128<<<N_NODES, 128, 0, stream>>>(rowptr, eidx, x, mean);
    k_dense1<<<(N_NODES + 127) / 128, 256, 0, stream>>>(mean, x, b1cat, b1, h);

    // ---- layer 2 ----
    k_dense2<<<(N_NODES + 127) / 128, 256, 0, stream>>>(h, b2cat, b2, z);
    k_gather40<<<N_NODES, 64, 0, stream>>>(rowptr, eidx, z, outp);
}